// Round 10
// baseline (153.397 us; speedup 1.0000x reference)
//
#include <hip/hip_runtime.h>
#include <hip/hip_cooperative_groups.h>
#include <math.h>

namespace cg = cooperative_groups;

#define Nn 8192
#define Dd 256
#define Kk 32

typedef float f4x __attribute__((ext_vector_type(4)));

// ws float layout:
// [0,        4194304)  P[k][gh][blk][d]   32*2*256*256  (16 MB partials, nt-streamed)
// [4194304,  4325376)  P2[tile][d]        512*256       (512 KB, level-2 partials)
// [4325376,  4333568)  Sp[k][blk]         32*256        (per-block gamma sums, k-major)
#define P_OFF   0
#define P2_OFF  4194304
#define SP_OFF  4325376

// Single cooperative kernel: 256 blocks x 1024 thr (1 block/CU, LDS-bound).
// Phase 1 = R8's K1 (gamma + partial G/H, nt P stores).
// Phase 2 = R8's vectorized K2 (2 tiles/block, nt loads).
// Phase 3 = K3 epilogue on blocks 0..31.
// grid.sync() between phases replaces 2 kernel launches + gaps.
__global__ __launch_bounds__(1024) void fused_all(const float* __restrict__ x,
                                                  const float* __restrict__ w,
                                                  const float* __restrict__ b,
                                                  float* __restrict__ ws,
                                                  float* __restrict__ out) {
    __shared__ __align__(16) float4 uS4[64 * 33];   // ~33.8 KB; phase-2 scratch alias
    __shared__ __align__(16) float4 vS4[64 * 33];   // ~33.8 KB
    __shared__ __align__(16) float4 xS4[32 * 64];   // 32 KB linear (DMA dest)
    __shared__ float  gS[1024];                     // gamma [r][k]; phase-3 sred alias

    float* P  = ws + P_OFF;
    float* P2 = ws + P2_OFF;
    float* Sp = ws + SP_OFF;
    int tid = threadIdx.x;
    int blk = blockIdx.x;

    // ================= phase 1: gamma + partial G/H =================
    {
        const float* xg = x + (size_t)blk * 32 * Dd;
        #pragma unroll
        for (int i = 0; i < 2; ++i) {
            int e4 = tid + i * 1024;
            __builtin_amdgcn_global_load_lds(
                (const __attribute__((address_space(1))) void*)(xg + (size_t)e4 * 4),
                (__attribute__((address_space(3))) void*)(&xS4[e4]),
                16, 0, 0);
        }
    }
    {
        const float4* w4 = (const float4*)w;
        const float4* b4 = (const float4*)b;
        #pragma unroll
        for (int i = 0; i < 2; ++i) {
            int e4 = tid + i * 1024;
            int k  = e4 >> 6;
            int d4 = e4 & 63;
            float4 wv = w4[e4];
            float4 bv = b4[e4];
            float4 vv = {wv.x * bv.x, wv.y * bv.y, wv.z * bv.z, wv.w * bv.w};
            uS4[d4 * 33 + k] = wv;
            vS4[d4 * 33 + k] = vv;
        }
    }
    __syncthreads();                          // drains vmcnt -> x DMA done too

    {
        int lane = tid & 63;
        int wave = tid >> 6;
        int k = lane & 31;
        int h = lane >> 5;
        int r0 = wave * 2;

        const float4* xr0 = &xS4[(r0 + 0) * 64];
        const float4* xr1 = &xS4[(r0 + 1) * 64];

        float4 a0 = {0.f, 0.f, 0.f, 0.f}, a1 = a0;

        #pragma unroll 8
        for (int i = 0; i < 32; ++i) {
            int ii = h * 32 + i;
            float4 u  = uS4[ii * 33 + k];
            float4 v  = vS4[ii * 33 + k];
            float4 x0 = xr0[ii];             // LDS broadcast within half-wave
            float4 x1 = xr1[ii];
            float y;
            y = fmaf(u.x, x0.x, v.x); a0.x = fmaf(y, y, a0.x);
            y = fmaf(u.y, x0.y, v.y); a0.y = fmaf(y, y, a0.y);
            y = fmaf(u.z, x0.z, v.z); a0.z = fmaf(y, y, a0.z);
            y = fmaf(u.w, x0.w, v.w); a0.w = fmaf(y, y, a0.w);
            y = fmaf(u.x, x1.x, v.x); a1.x = fmaf(y, y, a1.x);
            y = fmaf(u.y, x1.y, v.y); a1.y = fmaf(y, y, a1.y);
            y = fmaf(u.z, x1.z, v.z); a1.z = fmaf(y, y, a1.z);
            y = fmaf(u.w, x1.w, v.w); a1.w = fmaf(y, y, a1.w);
        }

        float s0 = (a0.x + a0.y) + (a0.z + a0.w);
        float s1 = (a1.x + a1.y) + (a1.z + a1.w);
        s0 += __shfl_xor(s0, 32);            // combine the two d-halves
        s1 += __shfl_xor(s1, 32);
        float y40 = -0.5f * s0, y41 = -0.5f * s1;

        float m0 = y40, m1 = y41;
        #pragma unroll
        for (int o = 16; o >= 1; o >>= 1) {
            m0 = fmaxf(m0, __shfl_xor(m0, o));
            m1 = fmaxf(m1, __shfl_xor(m1, o));
        }
        float e0 = __expf(y40 - m0), e1 = __expf(y41 - m1);
        float t0 = e0, t1 = e1;
        #pragma unroll
        for (int o = 16; o >= 1; o >>= 1) {
            t0 += __shfl_xor(t0, o);
            t1 += __shfl_xor(t1, o);
        }
        if (h == 0) {
            gS[(r0 + 0) * 32 + k] = e0 / t0;
            gS[(r0 + 1) * 32 + k] = e1 / t1;
        }
    }
    __syncthreads();

    if (tid < 32) {
        float s0 = 0.f, s1 = 0.f, s2 = 0.f, s3 = 0.f;
        #pragma unroll
        for (int r = 0; r < 32; r += 4) {
            s0 += gS[(r + 0) * 32 + tid];
            s1 += gS[(r + 1) * 32 + tid];
            s2 += gS[(r + 2) * 32 + tid];
            s3 += gS[(r + 3) * 32 + tid];
        }
        Sp[tid * 256 + blk] = (s0 + s1) + (s2 + s3);
    }

    {
        int kq = tid >> 8;                   // 0..3 -> k in [8*kq, 8*kq+8)
        int d  = tid & 255;
        const float* xl = (const float*)xS4;
        const float4* gS4 = (const float4*)gS;

        float aG[8], aH[8];
        #pragma unroll
        for (int j = 0; j < 8; ++j) { aG[j] = 0.f; aH[j] = 0.f; }

        #pragma unroll 4
        for (int r = 0; r < 32; ++r) {
            float xv = xl[r * 256 + d];
            float xx = xv * xv;
            #pragma unroll
            for (int q = 0; q < 2; ++q) {
                float4 gv = gS4[r * 8 + kq * 2 + q];   // wave-uniform -> broadcast
                aG[4*q+0] = fmaf(gv.x, xv, aG[4*q+0]); aH[4*q+0] = fmaf(gv.x, xx, aH[4*q+0]);
                aG[4*q+1] = fmaf(gv.y, xv, aG[4*q+1]); aH[4*q+1] = fmaf(gv.y, xx, aH[4*q+1]);
                aG[4*q+2] = fmaf(gv.z, xv, aG[4*q+2]); aH[4*q+2] = fmaf(gv.z, xx, aH[4*q+2]);
                aG[4*q+3] = fmaf(gv.w, xv, aG[4*q+3]); aH[4*q+3] = fmaf(gv.w, xx, aH[4*q+3]);
            }
        }

        #pragma unroll
        for (int j = 0; j < 8; ++j) {
            int k = kq * 8 + j;
            __builtin_nontemporal_store(aG[j], &P[((size_t)(k * 2 + 0) * 256 + blk) * 256 + d]);
            __builtin_nontemporal_store(aH[j], &P[((size_t)(k * 2 + 1) * 256 + blk) * 256 + d]);
        }
    }

    cg::this_grid().sync();

    // ================= phase 2: reduce P (2 tiles per block) =================
    {
        f4x* sT = (f4x*)uS4;                 // 16 KB scratch (phase-1 LDS dead)
        const f4x* P4  = (const f4x*)P;
        f4x*       P24 = (f4x*)P2;
        int half = tid >> 9;                 // 0..1
        int t    = blk * 2 + half;           // tile 0..511 (= (k*2+gh)*8 + c)
        int lt   = tid & 511;
        int c4   = lt & 63;                  // col4
        int g    = lt >> 6;                  // rowgroup 0..7 (4 rows each)

        const f4x* p = P4 + ((size_t)t * 32 + g * 4) * 64 + c4;
        f4x a0 = __builtin_nontemporal_load(&p[0]);
        f4x a1 = __builtin_nontemporal_load(&p[64]);
        a0 += __builtin_nontemporal_load(&p[128]);
        a1 += __builtin_nontemporal_load(&p[192]);
        sT[half * 512 + g * 64 + c4] = a0 + a1;
        __syncthreads();

        if (g == 0) {
            f4x s = sT[half * 512 + c4];
            #pragma unroll
            for (int j = 1; j < 8; ++j) s += sT[half * 512 + j * 64 + c4];
            P24[(size_t)t * 64 + c4] = s;
        }
    }

    cg::this_grid().sync();

    // ================= phase 3: epilogue (blocks 0..31) =================
    if (blk < 32) {
        int k = blk;
        float sv_part = 0.f;
        if (tid < 256) sv_part = Sp[k * 256 + tid];
        #pragma unroll
        for (int o = 32; o >= 1; o >>= 1) sv_part += __shfl_xor(sv_part, o);
        if (tid < 256 && (tid & 63) == 0) gS[tid >> 6] = sv_part;
        __syncthreads();
        if (tid < 256) {
            int d = tid;
            float sv = (gS[0] + gS[1]) + (gS[2] + gS[3]);
            const float* pg = P2 + (size_t)(k * 2 + 0) * 8 * 256 + d;
            const float* ph = P2 + (size_t)(k * 2 + 1) * 8 * 256 + d;
            float Gv = 0.f, Hv = 0.f;
            #pragma unroll
            for (int c = 0; c < 8; ++c) {
                Gv += pg[c * 256];
                Hv += ph[c * 256];
            }

            int idx = k * Dd + d;
            float wv = w[idx], bv = b[idx];
            const float invN = 1.0f / 8192.0f;
            const float c2 = 0.70710678118654752440f * invN;   // 1/(sqrt(2)*N)
            float mu = wv * (Gv + bv * sv) * invN;
            float w2 = wv * wv;
            float sg = (w2 * (Hv + 2.0f * bv * Gv + bv * bv * sv) - sv) * c2;
            out[idx] = sg;              // sigma_part
            out[Kk * Dd + idx] = mu;    // mu_part
        }
    }
}

extern "C" void kernel_launch(void* const* d_in, const int* in_sizes, int n_in,
                              void* d_out, int out_size, void* d_ws, size_t ws_size,
                              hipStream_t stream) {
    const float* x = (const float*)d_in[0];
    const float* w = (const float*)d_in[1];
    const float* b = (const float*)d_in[2];
    float* out = (float*)d_out;
    float* ws = (float*)d_ws;

    void* args[5] = {(void*)&x, (void*)&w, (void*)&b, (void*)&ws, (void*)&out};
    hipLaunchCooperativeKernel((const void*)fused_all, dim3(256), dim3(1024),
                               args, 0, stream);
}

// Round 11
// 78.024 us; speedup vs baseline: 1.9660x; 1.9660x over previous
//
#include <hip/hip_runtime.h>
#include <math.h>

#define Nn 8192
#define Dd 256
#define Kk 32

typedef float        f4x __attribute__((ext_vector_type(4)));
typedef unsigned int u2x __attribute__((ext_vector_type(2)));
typedef unsigned int u4x __attribute__((ext_vector_type(4)));

// ws layout:
// [0,        2097152)  P[k][gh][blk][d]  bf16 32*2*256*256 (8 MB partials, nt-streamed)
// [2097152,  2228224)  P2[tile][d]       f32  512*256      (512 KB, level-2 partials)
// [2228224,  2236416)  Sp[k][blk]        f32  32*256       (per-block gamma sums)
#define P2_OFF  2097152
#define SP_OFF  2228224

__device__ __forceinline__ unsigned bfpack(float a, float b) {   // RNE bf16 pair
    unsigned ua = __float_as_uint(a); ua += 0x7FFFu + ((ua >> 16) & 1u);
    unsigned ub = __float_as_uint(b); ub += 0x7FFFu + ((ub >> 16) & 1u);
    return (ua >> 16) | (ub & 0xFFFF0000u);
}
__device__ __forceinline__ void nt_store_bf4(unsigned short* p, f4x v) {
    u2x d2; d2.x = bfpack(v.x, v.y); d2.y = bfpack(v.z, v.w);
    __builtin_nontemporal_store(d2, (u2x*)p);                    // 8 B nt store
}
__device__ __forceinline__ float bflo(unsigned u) { return __uint_as_float(u << 16); }
__device__ __forceinline__ float bfhi(unsigned u) { return __uint_as_float(u & 0xFFFF0000u); }

// K1: fused gamma + partial G/H (R8 body; accumulate relayout 2k x 4d; bf16 nt P).
__global__ __launch_bounds__(1024) void fused_kernel(const float* __restrict__ x,
                                                     const float* __restrict__ w,
                                                     const float* __restrict__ b,
                                                     float* __restrict__ ws) {
    __shared__ __align__(16) float4 uS4[64 * 33];   // ~33.8 KB transposed pad+1
    __shared__ __align__(16) float4 vS4[64 * 33];   // ~33.8 KB
    __shared__ __align__(16) float4 xS4[32 * 64];   // 32 KB linear (DMA dest)
    __shared__ float  gS[1024];                     // gamma [r][k] 4 KB

    float* Sp = ws + SP_OFF;
    int tid = threadIdx.x;
    int blk = blockIdx.x;

    // ---- async DMA: x tile -> LDS (completes at the barrier) ----
    {
        const float* xg = x + (size_t)blk * 32 * Dd;
        #pragma unroll
        for (int i = 0; i < 2; ++i) {
            int e4 = tid + i * 1024;
            __builtin_amdgcn_global_load_lds(
                (const __attribute__((address_space(1))) void*)(xg + (size_t)e4 * 4),
                (__attribute__((address_space(3))) void*)(&xS4[e4]),
                16, 0, 0);
        }
    }

    // ---- stage + transpose w, w*b into LDS (overlaps the x DMA) ----
    {
        const float4* w4 = (const float4*)w;
        const float4* b4 = (const float4*)b;
        #pragma unroll
        for (int i = 0; i < 2; ++i) {
            int e4 = tid + i * 1024;
            int k  = e4 >> 6;
            int d4 = e4 & 63;
            float4 wv = w4[e4];
            float4 bv = b4[e4];
            float4 vv = {wv.x * bv.x, wv.y * bv.y, wv.z * bv.z, wv.w * bv.w};
            uS4[d4 * 33 + k] = wv;
            vS4[d4 * 33 + k] = vv;
        }
    }
    __syncthreads();                          // drains vmcnt -> x DMA done too

    // ---- gamma: 16 waves x 2 rows; u,v,x all from LDS ----
    {
        int lane = tid & 63;
        int wave = tid >> 6;
        int k = lane & 31;
        int h = lane >> 5;
        int r0 = wave * 2;

        const float4* xr0 = &xS4[(r0 + 0) * 64];
        const float4* xr1 = &xS4[(r0 + 1) * 64];

        float4 a0 = {0.f, 0.f, 0.f, 0.f}, a1 = a0;

        #pragma unroll 8
        for (int i = 0; i < 32; ++i) {
            int ii = h * 32 + i;
            float4 u  = uS4[ii * 33 + k];
            float4 v  = vS4[ii * 33 + k];
            float4 x0 = xr0[ii];             // LDS broadcast within half-wave
            float4 x1 = xr1[ii];
            float y;
            y = fmaf(u.x, x0.x, v.x); a0.x = fmaf(y, y, a0.x);
            y = fmaf(u.y, x0.y, v.y); a0.y = fmaf(y, y, a0.y);
            y = fmaf(u.z, x0.z, v.z); a0.z = fmaf(y, y, a0.z);
            y = fmaf(u.w, x0.w, v.w); a0.w = fmaf(y, y, a0.w);
            y = fmaf(u.x, x1.x, v.x); a1.x = fmaf(y, y, a1.x);
            y = fmaf(u.y, x1.y, v.y); a1.y = fmaf(y, y, a1.y);
            y = fmaf(u.z, x1.z, v.z); a1.z = fmaf(y, y, a1.z);
            y = fmaf(u.w, x1.w, v.w); a1.w = fmaf(y, y, a1.w);
        }

        float s0 = (a0.x + a0.y) + (a0.z + a0.w);
        float s1 = (a1.x + a1.y) + (a1.z + a1.w);
        s0 += __shfl_xor(s0, 32);            // combine the two d-halves
        s1 += __shfl_xor(s1, 32);
        float y40 = -0.5f * s0, y41 = -0.5f * s1;

        float m0 = y40, m1 = y41;
        #pragma unroll
        for (int o = 16; o >= 1; o >>= 1) {
            m0 = fmaxf(m0, __shfl_xor(m0, o));
            m1 = fmaxf(m1, __shfl_xor(m1, o));
        }
        float e0 = __expf(y40 - m0), e1 = __expf(y41 - m1);
        float t0 = e0, t1 = e1;
        #pragma unroll
        for (int o = 16; o >= 1; o >>= 1) {
            t0 += __shfl_xor(t0, o);
            t1 += __shfl_xor(t1, o);
        }
        if (h == 0) {
            gS[(r0 + 0) * 32 + k] = e0 / t0;
            gS[(r0 + 1) * 32 + k] = e1 / t1;
        }
    }
    __syncthreads();

    // ---- per-block gamma sums -> Sp[k][blk] (k-major: K3 reads coalesced) ----
    if (tid < 32) {
        float s0 = 0.f, s1 = 0.f, s2 = 0.f, s3 = 0.f;
        #pragma unroll
        for (int r = 0; r < 32; r += 4) {
            s0 += gS[(r + 0) * 32 + tid];
            s1 += gS[(r + 1) * 32 + tid];
            s2 += gS[(r + 2) * 32 + tid];
            s3 += gS[(r + 3) * 32 + tid];
        }
        Sp[tid * 256 + blk] = (s0 + s1) + (s2 + s3);
    }

    // ---- accumulate: thread = (kg: 2 k's, d4: 4 d's) ----
    // per r: 1 ds_read_b128 (x, per-lane) + 1 uniform b64 (gamma pair) -> 16 FMA
    {
        int kg = tid >> 6;                   // 0..15 -> k in {2kg, 2kg+1}
        int d4 = tid & 63;                   // float4 column (4 consecutive d)
        const f4x* xl4 = (const f4x*)xS4;    // [r*64 + d4]
        const float2* gS2 = (const float2*)gS;

        f4x aG0 = {0.f, 0.f, 0.f, 0.f}, aH0 = aG0, aG1 = aG0, aH1 = aG0;

        #pragma unroll 4
        for (int r = 0; r < 32; ++r) {
            f4x xv = xl4[r * 64 + d4];
            f4x xx = xv * xv;
            float2 g2 = gS2[r * 16 + kg];    // wave-uniform -> broadcast
            aG0 += g2.x * xv;  aH0 += g2.x * xx;
            aG1 += g2.y * xv;  aH1 += g2.y * xx;
        }

        unsigned short* Pb = (unsigned short*)ws;
        int k0 = kg * 2, k1 = k0 + 1;
        size_t dd = (size_t)4 * d4;
        nt_store_bf4(Pb + ((size_t)(k0 * 2 + 0) * 256 + blk) * 256 + dd, aG0);
        nt_store_bf4(Pb + ((size_t)(k0 * 2 + 1) * 256 + blk) * 256 + dd, aH0);
        nt_store_bf4(Pb + ((size_t)(k1 * 2 + 0) * 256 + blk) * 256 + dd, aG1);
        nt_store_bf4(Pb + ((size_t)(k1 * 2 + 1) * 256 + blk) * 256 + dd, aH1);
    }
}

// K2: 512 blocks x 256 thr; block t reduces rows [32t,32t+32) of the
// [16384][256] bf16 P view. u4x nt loads (bf16x8 = 16 B/lane), f32 accum,
// LDS combine, f32 P2 store. t = (k*2+gh)*8 + c, matching K3.
__global__ __launch_bounds__(256) void red1_kernel(float* __restrict__ ws) {
    const unsigned short* Pb = (const unsigned short*)ws;
    f4x* P24 = (f4x*)(ws + P2_OFF);
    __shared__ __align__(16) f4x sT[512];
    int tid = threadIdx.x;
    int cb = tid & 31;                       // bf16x8 column group (8 d's)
    int g  = tid >> 5;                       // rowgroup 0..7 (4 rows each)

    const u4x* p = (const u4x*)(Pb + ((size_t)blockIdx.x * 32 + g * 4) * 256 + cb * 8);
    f4x a0 = {0.f, 0.f, 0.f, 0.f}, a1 = a0;
    #pragma unroll
    for (int j = 0; j < 4; ++j) {
        u4x v = __builtin_nontemporal_load(&p[(size_t)j * 32]);  // row = 32 u4x
        a0.x += bflo(v.x); a0.y += bfhi(v.x); a0.z += bflo(v.y); a0.w += bfhi(v.y);
        a1.x += bflo(v.z); a1.y += bfhi(v.z); a1.z += bflo(v.w); a1.w += bfhi(v.w);
    }
    sT[(g * 32 + cb) * 2 + 0] = a0;
    sT[(g * 32 + cb) * 2 + 1] = a1;
    __syncthreads();

    if (g == 0) {
        f4x s0 = sT[cb * 2], s1 = sT[cb * 2 + 1];
        #pragma unroll
        for (int j = 1; j < 8; ++j) {
            s0 += sT[(j * 32 + cb) * 2 + 0];
            s1 += sT[(j * 32 + cb) * 2 + 1];
        }
        P24[(size_t)blockIdx.x * 64 + cb * 2 + 0] = s0;   // d = 8cb..8cb+3
        P24[(size_t)blockIdx.x * 64 + cb * 2 + 1] = s1;   // d = 8cb+4..8cb+7
    }
}

// K3: 32 blocks x 256 thr; block=k, thread=d. Final sums + S + epilogue.
__global__ __launch_bounds__(256) void red2_kernel(const float* __restrict__ w,
                                                   const float* __restrict__ b,
                                                   const float* __restrict__ ws,
                                                   float* __restrict__ out) {
    const float* P2 = ws + P2_OFF;
    const float* Sp = ws + SP_OFF;
    __shared__ float sred[4];
    int k = blockIdx.x, d = threadIdx.x;

    // ---- S[k] = sum over 256 blocks (coalesced: Sp is k-major) ----
    float sv_part = Sp[k * 256 + d];
    #pragma unroll
    for (int o = 32; o >= 1; o >>= 1) sv_part += __shfl_xor(sv_part, o);
    if ((d & 63) == 0) sred[d >> 6] = sv_part;
    __syncthreads();
    float sv = (sred[0] + sred[1]) + (sred[2] + sred[3]);

    const float* pg = P2 + (size_t)(k * 2 + 0) * 8 * 256 + d;
    const float* ph = P2 + (size_t)(k * 2 + 1) * 8 * 256 + d;
    float Gv = 0.f, Hv = 0.f;
    #pragma unroll
    for (int c = 0; c < 8; ++c) {
        Gv += pg[c * 256];
        Hv += ph[c * 256];
    }

    int idx = k * Dd + d;
    float wv = w[idx], bv = b[idx];
    const float invN = 1.0f / 8192.0f;
    const float c2 = 0.70710678118654752440f * invN;   // 1/(sqrt(2)*N)
    float mu = wv * (Gv + bv * sv) * invN;
    float w2 = wv * wv;
    float sg = (w2 * (Hv + 2.0f * bv * Gv + bv * bv * sv) - sv) * c2;
    out[idx] = sg;              // sigma_part
    out[Kk * Dd + idx] = mu;    // mu_part
}

extern "C" void kernel_launch(void* const* d_in, const int* in_sizes, int n_in,
                              void* d_out, int out_size, void* d_ws, size_t ws_size,
                              hipStream_t stream) {
    const float* x = (const float*)d_in[0];
    const float* w = (const float*)d_in[1];
    const float* b = (const float*)d_in[2];
    float* out = (float*)d_out;
    float* ws = (float*)d_ws;

    hipLaunchKernelGGL(fused_kernel, dim3(256), dim3(1024), 0, stream, x, w, b, ws);
    hipLaunchKernelGGL(red1_kernel,  dim3(512), dim3(256),  0, stream, ws);
    hipLaunchKernelGGL(red2_kernel,  dim3(32),  dim3(256),  0, stream, w, b, ws, out);
}

// Round 12
// 76.251 us; speedup vs baseline: 2.0117x; 1.0233x over previous
//
#include <hip/hip_runtime.h>
#include <math.h>

#define Nn 8192
#define Dd 256
#define Kk 32

typedef float        f4x __attribute__((ext_vector_type(4)));
typedef unsigned int u2x __attribute__((ext_vector_type(2)));
typedef unsigned int u4x __attribute__((ext_vector_type(4)));

// ws layout:
// [0,        2097152)  P[k][gh][blk][d]  bf16 32*2*256*256 (8 MB partials, nt-streamed)
// [2228224,  2236416)  Sp[k][blk]        f32  32*256       (per-block gamma sums)
#define SP_OFF  2228224

__device__ __forceinline__ unsigned bfpack(float a, float b) {   // RNE bf16 pair
    unsigned ua = __float_as_uint(a); ua += 0x7FFFu + ((ua >> 16) & 1u);
    unsigned ub = __float_as_uint(b); ub += 0x7FFFu + ((ub >> 16) & 1u);
    return (ua >> 16) | (ub & 0xFFFF0000u);
}
__device__ __forceinline__ void nt_store_bf4(unsigned short* p, f4x v) {
    u2x d2; d2.x = bfpack(v.x, v.y); d2.y = bfpack(v.z, v.w);
    __builtin_nontemporal_store(d2, (u2x*)p);                    // 8 B nt store
}
__device__ __forceinline__ float bflo(unsigned u) { return __uint_as_float(u << 16); }
__device__ __forceinline__ float bfhi(unsigned u) { return __uint_as_float(u & 0xFFFF0000u); }

// K1: fused gamma + partial G/H (R11 body) + zeroing of `out` (64 floats/block;
// stream order guarantees visibility before K2's atomics).
__global__ __launch_bounds__(1024) void fused_kernel(const float* __restrict__ x,
                                                     const float* __restrict__ w,
                                                     const float* __restrict__ b,
                                                     float* __restrict__ ws,
                                                     float* __restrict__ out) {
    __shared__ __align__(16) float4 uS4[64 * 33];   // ~33.8 KB transposed pad+1
    __shared__ __align__(16) float4 vS4[64 * 33];   // ~33.8 KB
    __shared__ __align__(16) float4 xS4[32 * 64];   // 32 KB linear (DMA dest)
    __shared__ float  gS[1024];                     // gamma [r][k] 4 KB

    float* Sp = ws + SP_OFF;
    int tid = threadIdx.x;
    int blk = blockIdx.x;

    // ---- zero the output accumulators (2*32*256 = 16384 floats / 256 blocks) ----
    if (tid < 64) out[blk * 64 + tid] = 0.f;

    // ---- async DMA: x tile -> LDS (completes at the barrier) ----
    {
        const float* xg = x + (size_t)blk * 32 * Dd;
        #pragma unroll
        for (int i = 0; i < 2; ++i) {
            int e4 = tid + i * 1024;
            __builtin_amdgcn_global_load_lds(
                (const __attribute__((address_space(1))) void*)(xg + (size_t)e4 * 4),
                (__attribute__((address_space(3))) void*)(&xS4[e4]),
                16, 0, 0);
        }
    }

    // ---- stage + transpose w, w*b into LDS (overlaps the x DMA) ----
    {
        const float4* w4 = (const float4*)w;
        const float4* b4 = (const float4*)b;
        #pragma unroll
        for (int i = 0; i < 2; ++i) {
            int e4 = tid + i * 1024;
            int k  = e4 >> 6;
            int d4 = e4 & 63;
            float4 wv = w4[e4];
            float4 bv = b4[e4];
            float4 vv = {wv.x * bv.x, wv.y * bv.y, wv.z * bv.z, wv.w * bv.w};
            uS4[d4 * 33 + k] = wv;
            vS4[d4 * 33 + k] = vv;
        }
    }
    __syncthreads();                          // drains vmcnt -> x DMA done too

    // ---- gamma: 16 waves x 2 rows; u,v,x all from LDS ----
    {
        int lane = tid & 63;
        int wave = tid >> 6;
        int k = lane & 31;
        int h = lane >> 5;
        int r0 = wave * 2;

        const float4* xr0 = &xS4[(r0 + 0) * 64];
        const float4* xr1 = &xS4[(r0 + 1) * 64];

        float4 a0 = {0.f, 0.f, 0.f, 0.f}, a1 = a0;

        #pragma unroll 8
        for (int i = 0; i < 32; ++i) {
            int ii = h * 32 + i;
            float4 u  = uS4[ii * 33 + k];
            float4 v  = vS4[ii * 33 + k];
            float4 x0 = xr0[ii];             // LDS broadcast within half-wave
            float4 x1 = xr1[ii];
            float y;
            y = fmaf(u.x, x0.x, v.x); a0.x = fmaf(y, y, a0.x);
            y = fmaf(u.y, x0.y, v.y); a0.y = fmaf(y, y, a0.y);
            y = fmaf(u.z, x0.z, v.z); a0.z = fmaf(y, y, a0.z);
            y = fmaf(u.w, x0.w, v.w); a0.w = fmaf(y, y, a0.w);
            y = fmaf(u.x, x1.x, v.x); a1.x = fmaf(y, y, a1.x);
            y = fmaf(u.y, x1.y, v.y); a1.y = fmaf(y, y, a1.y);
            y = fmaf(u.z, x1.z, v.z); a1.z = fmaf(y, y, a1.z);
            y = fmaf(u.w, x1.w, v.w); a1.w = fmaf(y, y, a1.w);
        }

        float s0 = (a0.x + a0.y) + (a0.z + a0.w);
        float s1 = (a1.x + a1.y) + (a1.z + a1.w);
        s0 += __shfl_xor(s0, 32);            // combine the two d-halves
        s1 += __shfl_xor(s1, 32);
        float y40 = -0.5f * s0, y41 = -0.5f * s1;

        float m0 = y40, m1 = y41;
        #pragma unroll
        for (int o = 16; o >= 1; o >>= 1) {
            m0 = fmaxf(m0, __shfl_xor(m0, o));
            m1 = fmaxf(m1, __shfl_xor(m1, o));
        }
        float e0 = __expf(y40 - m0), e1 = __expf(y41 - m1);
        float t0 = e0, t1 = e1;
        #pragma unroll
        for (int o = 16; o >= 1; o >>= 1) {
            t0 += __shfl_xor(t0, o);
            t1 += __shfl_xor(t1, o);
        }
        if (h == 0) {
            gS[(r0 + 0) * 32 + k] = e0 / t0;
            gS[(r0 + 1) * 32 + k] = e1 / t1;
        }
    }
    __syncthreads();

    // ---- per-block gamma sums -> Sp[k][blk] ----
    if (tid < 32) {
        float s0 = 0.f, s1 = 0.f, s2 = 0.f, s3 = 0.f;
        #pragma unroll
        for (int r = 0; r < 32; r += 4) {
            s0 += gS[(r + 0) * 32 + tid];
            s1 += gS[(r + 1) * 32 + tid];
            s2 += gS[(r + 2) * 32 + tid];
            s3 += gS[(r + 3) * 32 + tid];
        }
        Sp[tid * 256 + blk] = (s0 + s1) + (s2 + s3);
    }

    // ---- accumulate: thread = (kg: 2 k's, d4: 4 d's); bf16 nt P stores ----
    {
        int kg = tid >> 6;                   // 0..15 -> k in {2kg, 2kg+1}
        int d4 = tid & 63;                   // float4 column (4 consecutive d)
        const f4x* xl4 = (const f4x*)xS4;    // [r*64 + d4]
        const float2* gS2 = (const float2*)gS;

        f4x aG0 = {0.f, 0.f, 0.f, 0.f}, aH0 = aG0, aG1 = aG0, aH1 = aG0;

        #pragma unroll 4
        for (int r = 0; r < 32; ++r) {
            f4x xv = xl4[r * 64 + d4];
            f4x xx = xv * xv;
            float2 g2 = gS2[r * 16 + kg];    // wave-uniform -> broadcast
            aG0 += g2.x * xv;  aH0 += g2.x * xx;
            aG1 += g2.y * xv;  aH1 += g2.y * xx;
        }

        unsigned short* Pb = (unsigned short*)ws;
        int k0 = kg * 2, k1 = k0 + 1;
        size_t dd = (size_t)4 * d4;
        nt_store_bf4(Pb + ((size_t)(k0 * 2 + 0) * 256 + blk) * 256 + dd, aG0);
        nt_store_bf4(Pb + ((size_t)(k0 * 2 + 1) * 256 + blk) * 256 + dd, aH0);
        nt_store_bf4(Pb + ((size_t)(k1 * 2 + 0) * 256 + blk) * 256 + dd, aG1);
        nt_store_bf4(Pb + ((size_t)(k1 * 2 + 1) * 256 + blk) * 256 + dd, aH1);
    }
}

// K2 (final): 512 blocks x 256 thr; block (k,gh,c) reduces its 32-row chunk of
// bf16 P, then atomically adds its FINAL-SCALED contribution to out (epilogue is
// linear in the chunk partials). Blocks (k,gh=0,c=0) also fold in the sv terms.
// No P2, no K3, no device-side sync — stream order only.
__global__ __launch_bounds__(256) void red_final(const float* __restrict__ w,
                                                 const float* __restrict__ b,
                                                 const float* __restrict__ ws,
                                                 float* __restrict__ out) {
    const unsigned short* Pb = (const unsigned short*)ws;
    const float* Sp = ws + SP_OFF;
    __shared__ __align__(16) f4x sT[512];
    __shared__ float sred[4];
    int tid = threadIdx.x;
    int cb = tid & 31;                       // bf16x8 column group (8 d's)
    int g  = tid >> 5;                       // rowgroup 0..7 (4 rows each)
    int bid = blockIdx.x;
    int k  = bid >> 4;
    int gh = (bid >> 3) & 1;
    int c  = bid & 7;

    // ---- chunk reduction: rows [bid*32, bid*32+32) of the [16384][256] view ----
    const u4x* p = (const u4x*)(Pb + ((size_t)bid * 32 + g * 4) * 256 + cb * 8);
    f4x a0 = {0.f, 0.f, 0.f, 0.f}, a1 = a0;
    #pragma unroll
    for (int j = 0; j < 4; ++j) {
        u4x v = __builtin_nontemporal_load(&p[(size_t)j * 32]);  // row = 32 u4x
        a0.x += bflo(v.x); a0.y += bfhi(v.x); a0.z += bflo(v.y); a0.w += bfhi(v.y);
        a1.x += bflo(v.z); a1.y += bfhi(v.z); a1.z += bflo(v.w); a1.w += bfhi(v.w);
    }
    sT[(g * 32 + cb) * 2 + 0] = a0;          // float layout: sTf[g*256 + d]
    sT[(g * 32 + cb) * 2 + 1] = a1;
    __syncthreads();

    // ---- per-thread d: combine 8 rowgroups (stride-1, conflict-free) ----
    int d = tid;
    const float* sTf = (const float*)sT;
    float s = 0.f;
    #pragma unroll
    for (int j = 0; j < 8; ++j) s += sTf[j * 256 + d];

    int idx = k * Dd + d;
    float wv = w[idx], bv = b[idx];
    const float invN = 1.0f / 8192.0f;
    const float c2 = 0.70710678118654752440f * invN;   // 1/(sqrt(2)*N)
    float w2 = wv * wv;

    float sg_c, mu_c;
    if (gh == 0) {                            // s = G-chunk
        mu_c = wv * s * invN;
        sg_c = w2 * 2.0f * bv * s * c2;
    } else {                                  // s = H-chunk
        mu_c = 0.f;
        sg_c = w2 * s * c2;
    }

    if (gh == 0 && c == 0) {                  // fold in the sv terms (once per k)
        float svp = Sp[k * 256 + tid];
        #pragma unroll
        for (int o = 32; o >= 1; o >>= 1) svp += __shfl_xor(svp, o);
        if ((tid & 63) == 0) sred[tid >> 6] = svp;
        __syncthreads();
        float sv = (sred[0] + sred[1]) + (sred[2] + sred[3]);
        sg_c += (w2 * bv * bv - 1.0f) * sv * c2;
        mu_c += wv * bv * sv * invN;
    }

    atomicAdd(&out[idx], sg_c);               // sigma_part
    if (gh == 0) atomicAdd(&out[Kk * Dd + idx], mu_c);   // mu_part
}

extern "C" void kernel_launch(void* const* d_in, const int* in_sizes, int n_in,
                              void* d_out, int out_size, void* d_ws, size_t ws_size,
                              hipStream_t stream) {
    const float* x = (const float*)d_in[0];
    const float* w = (const float*)d_in[1];
    const float* b = (const float*)d_in[2];
    float* out = (float*)d_out;
    float* ws = (float*)d_ws;

    hipLaunchKernelGGL(fused_kernel, dim3(256), dim3(1024), 0, stream, x, w, b, ws, out);
    hipLaunchKernelGGL(red_final,    dim3(512), dim3(256),  0, stream, w, b, ws, out);
}